// Round 1
// baseline (232.634 us; speedup 1.0000x reference)
//
#include <hip/hip_runtime.h>

#define N_AG   128
#define H_DIM  128
#define IN_DIM 132
#define P_PAIRS 8128   // 128*127/2

__global__ void zero_out_kernel(float* out, int n) {
    int t = blockIdx.x * blockDim.x + threadIdx.x;
    if (t < n) out[t] = 0.f;
}

__global__ __launch_bounds__(256) void pair_mlp_kernel(
    const float* __restrict__ state,
    const float* __restrict__ actions,
    const float* __restrict__ W1,
    const float* __restrict__ b1,
    const float* __restrict__ W2,
    const float* __restrict__ b2,
    const float* __restrict__ W3,
    const float* __restrict__ b3,
    float* __restrict__ out)
{
    const int p = blockIdx.x;
    const int t = threadIdx.x;

    __shared__ float xs[IN_DIM];
    __shared__ float part[8][32][4];   // 4 KB partial sums
    __shared__ float h1s[H_DIM];
    __shared__ float h2s[H_DIM];
    __shared__ float r0[4], r1[4];

    // recover (i, j) in np.triu_indices(n,1) order: block-uniform scalar loop
    int i = 0, rem = p;
    while (rem >= (N_AG - 1 - i)) { rem -= (N_AG - 1 - i); ++i; }
    const int j = i + 1 + rem;

    if (t < 128)      xs[t]   = state[t];
    else if (t == 128) xs[128] = (float)i;
    else if (t == 129) xs[129] = (float)j;
    else if (t == 130) xs[130] = actions[i];
    else if (t == 131) xs[131] = actions[j];
    __syncthreads();

    const int c = t & 31;   // float4 column (h = 4c..4c+3)
    const int g = t >> 5;   // row group 0..7

    // ---- layer 1: h1 = relu(x @ W1[p] + b1[p]) ----
    const float4* W1p = (const float4*)(W1 + (size_t)p * (IN_DIM * H_DIM));
    float4 acc = make_float4(0.f, 0.f, 0.f, 0.f);
    for (int ii = g; ii < IN_DIM; ii += 8) {
        float xv = xs[ii];
        float4 w = W1p[ii * 32 + c];
        acc.x = fmaf(xv, w.x, acc.x);
        acc.y = fmaf(xv, w.y, acc.y);
        acc.z = fmaf(xv, w.z, acc.z);
        acc.w = fmaf(xv, w.w, acc.w);
    }
    *(float4*)&part[g][c][0] = acc;
    __syncthreads();
    if (t < H_DIM) {
        float s = b1[(size_t)p * H_DIM + t];
        const int cc = t >> 2, comp = t & 3;
        #pragma unroll
        for (int gg = 0; gg < 8; ++gg) s += part[gg][cc][comp];
        h1s[t] = fmaxf(s, 0.f);
    }
    __syncthreads();

    // ---- layer 2: h2 = relu(h1 @ W2[p] + b2[p]) ----
    const float4* W2p = (const float4*)(W2 + (size_t)p * (H_DIM * H_DIM));
    acc = make_float4(0.f, 0.f, 0.f, 0.f);
    for (int hh = g; hh < H_DIM; hh += 8) {
        float hv = h1s[hh];
        float4 w = W2p[hh * 32 + c];
        acc.x = fmaf(hv, w.x, acc.x);
        acc.y = fmaf(hv, w.y, acc.y);
        acc.z = fmaf(hv, w.z, acc.z);
        acc.w = fmaf(hv, w.w, acc.w);
    }
    *(float4*)&part[g][c][0] = acc;
    __syncthreads();
    if (t < H_DIM) {
        float s = b2[(size_t)p * H_DIM + t];
        const int cc = t >> 2, comp = t & 3;
        #pragma unroll
        for (int gg = 0; gg < 8; ++gg) s += part[gg][cc][comp];
        h2s[t] = fmaxf(s, 0.f);
    }
    __syncthreads();

    // ---- layer 3: logits = h2 @ W3[p] + b3[p]; softmax; scatter-add ----
    float p0 = 0.f, p1 = 0.f;
    if (t < H_DIM) {
        float v = h2s[t];
        float2 w3 = ((const float2*)(W3 + (size_t)p * (H_DIM * 2)))[t];
        p0 = v * w3.x;
        p1 = v * w3.y;
    }
    #pragma unroll
    for (int off = 32; off > 0; off >>= 1) {
        p0 += __shfl_down(p0, off, 64);
        p1 += __shfl_down(p1, off, 64);
    }
    const int wid = t >> 6;
    if ((t & 63) == 0) { r0[wid] = p0; r1[wid] = p1; }
    __syncthreads();
    if (t == 0) {
        float l0 = r0[0] + r0[1] + r0[2] + r0[3] + b3[2 * p];
        float l1 = r1[0] + r1[1] + r1[2] + r1[3] + b3[2 * p + 1];
        float m  = fmaxf(l0, l1);
        float e0 = expf(l0 - m), e1 = expf(l1 - m);
        float inv = 1.f / (e0 + e1);
        float g0 = e0 * inv, g1 = e1 * inv;
        atomicAdd(&out[2 * i],     g0);
        atomicAdd(&out[2 * i + 1], g1);
        atomicAdd(&out[2 * j],     g0);
        atomicAdd(&out[2 * j + 1], g1);
    }
}

extern "C" void kernel_launch(void* const* d_in, const int* in_sizes, int n_in,
                              void* d_out, int out_size, void* d_ws, size_t ws_size,
                              hipStream_t stream) {
    const float* state   = (const float*)d_in[0];
    const float* actions = (const float*)d_in[1];
    const float* W1      = (const float*)d_in[2];
    const float* b1      = (const float*)d_in[3];
    const float* W2      = (const float*)d_in[4];
    const float* b2      = (const float*)d_in[5];
    const float* W3      = (const float*)d_in[6];
    const float* b3      = (const float*)d_in[7];
    float* out = (float*)d_out;

    zero_out_kernel<<<1, 256, 0, stream>>>(out, out_size);
    pair_mlp_kernel<<<P_PAIRS, 256, 0, stream>>>(
        state, actions, W1, b1, W2, b2, W3, b3, out);
}

// Round 3
// 227.549 us; speedup vs baseline: 1.0223x; 1.0223x over previous
//
#include <hip/hip_runtime.h>

#define N_AG    128
#define H_DIM   128
#define IN_DIM  132
#define P_PAIRS 8128   // 128*127/2

typedef float f32x4 __attribute__((ext_vector_type(4)));

// closed-form recovery of (i,j) from pair index p (np.triu_indices order)
__device__ __forceinline__ void pair_from_p(int p, int& i, int& j) {
    int t = P_PAIRS - 1 - p;                  // reverse index: t=0 is (N-2,N-1)
    float kf = (sqrtf(8.f * (float)t + 1.f) - 1.f) * 0.5f;
    int k = (int)kf;
    while ((k + 1) * (k + 2) / 2 <= t) ++k;   // fixup fp error
    while (k * (k + 1) / 2 > t) --k;
    i = N_AG - 2 - k;
    j = N_AG - 1 - (t - k * (k + 1) / 2);
}

// ---------------- layer 1: h1[p] = relu(x_p @ W1[p] + b1[p]) ----------------
__global__ __launch_bounds__(256) void l1_kernel(
    const float* __restrict__ state,
    const float* __restrict__ actions,
    const float* __restrict__ W1,
    const float* __restrict__ b1,
    float* __restrict__ h1,     // [P, H] in d_ws
    float* __restrict__ out)    // zeroed here (block 0) for l23's atomics
{
    const int p = blockIdx.x;
    const int t = threadIdx.x;

    if (p == 0) out[t] = 0.f;   // out_size == 256 == blockDim

    __shared__ float xs[IN_DIM];
    __shared__ float part[8][32][4];

    int i, j;
    pair_from_p(p, i, j);

    if (t < 128)       xs[t]   = state[t];
    else if (t == 128) xs[128] = (float)i;
    else if (t == 129) xs[129] = (float)j;
    else if (t == 130) xs[130] = actions[i];
    else if (t == 131) xs[131] = actions[j];
    __syncthreads();

    const int c = t & 31;   // float4 column (h = 4c..4c+3)
    const int g = t >> 5;   // row group 0..7

    const f32x4* W1p = (const f32x4*)(W1 + (size_t)p * (IN_DIM * H_DIM));
    f32x4 acc = (f32x4)(0.f);
    #pragma unroll 8
    for (int r = 0; r < 16; ++r) {           // constant trip: rows g, g+8, ..., g+120
        const int ii = g + 8 * r;
        const float xv = xs[ii];
        const f32x4 w = __builtin_nontemporal_load(&W1p[ii * 32 + c]);
        acc.x = fmaf(xv, w.x, acc.x);
        acc.y = fmaf(xv, w.y, acc.y);
        acc.z = fmaf(xv, w.z, acc.z);
        acc.w = fmaf(xv, w.w, acc.w);
    }
    if (g < 4) {                              // epilogue rows 128..131
        const int ii = 128 + g;
        const float xv = xs[ii];
        const f32x4 w = __builtin_nontemporal_load(&W1p[ii * 32 + c]);
        acc.x = fmaf(xv, w.x, acc.x);
        acc.y = fmaf(xv, w.y, acc.y);
        acc.z = fmaf(xv, w.z, acc.z);
        acc.w = fmaf(xv, w.w, acc.w);
    }
    *(f32x4*)&part[g][c][0] = acc;
    __syncthreads();

    if (t < H_DIM) {
        float s = b1[(size_t)p * H_DIM + t];
        const int cc = t >> 2, comp = t & 3;
        #pragma unroll
        for (int gg = 0; gg < 8; ++gg) s += part[gg][cc][comp];
        h1[(size_t)p * H_DIM + t] = fmaxf(s, 0.f);
    }
}

// ------------- layers 2+3: softmax(relu(h1@W2+b2)@W3+b3) scatter-add -------------
__global__ __launch_bounds__(256) void l23_kernel(
    const float* __restrict__ h1,
    const float* __restrict__ W2,
    const float* __restrict__ b2,
    const float* __restrict__ W3,
    const float* __restrict__ b3,
    float* __restrict__ out)
{
    const int p = blockIdx.x;
    const int t = threadIdx.x;

    __shared__ float h1s[H_DIM];
    __shared__ float part[8][32][4];
    __shared__ float h2s[H_DIM];
    __shared__ float r0[4], r1[4];

    int i, j;
    pair_from_p(p, i, j);

    if (t < H_DIM) h1s[t] = h1[(size_t)p * H_DIM + t];
    __syncthreads();

    const int c = t & 31;
    const int g = t >> 5;

    const f32x4* W2p = (const f32x4*)(W2 + (size_t)p * (H_DIM * H_DIM));
    f32x4 acc = (f32x4)(0.f);
    #pragma unroll 8
    for (int r = 0; r < 16; ++r) {           // constant trip: 128/8
        const int hh = g + 8 * r;
        const float hv = h1s[hh];
        const f32x4 w = __builtin_nontemporal_load(&W2p[hh * 32 + c]);
        acc.x = fmaf(hv, w.x, acc.x);
        acc.y = fmaf(hv, w.y, acc.y);
        acc.z = fmaf(hv, w.z, acc.z);
        acc.w = fmaf(hv, w.w, acc.w);
    }
    *(f32x4*)&part[g][c][0] = acc;
    __syncthreads();

    if (t < H_DIM) {
        float s = b2[(size_t)p * H_DIM + t];
        const int cc = t >> 2, comp = t & 3;
        #pragma unroll
        for (int gg = 0; gg < 8; ++gg) s += part[gg][cc][comp];
        h2s[t] = fmaxf(s, 0.f);
    }
    __syncthreads();

    // layer 3 + softmax + scatter
    float p0 = 0.f, p1 = 0.f;
    if (t < H_DIM) {
        const float v = h2s[t];
        const float2 w3 = ((const float2*)(W3 + (size_t)p * (H_DIM * 2)))[t];
        p0 = v * w3.x;
        p1 = v * w3.y;
    }
    #pragma unroll
    for (int off = 32; off > 0; off >>= 1) {
        p0 += __shfl_down(p0, off, 64);
        p1 += __shfl_down(p1, off, 64);
    }
    const int wid = t >> 6;
    if ((t & 63) == 0) { r0[wid] = p0; r1[wid] = p1; }
    __syncthreads();
    if (t == 0) {
        const float l0 = r0[0] + r0[1] + b3[2 * p];
        const float l1 = r1[0] + r1[1] + b3[2 * p + 1];
        const float m  = fmaxf(l0, l1);
        const float e0 = expf(l0 - m), e1 = expf(l1 - m);
        const float inv = 1.f / (e0 + e1);
        const float g0 = e0 * inv, g1 = e1 * inv;
        atomicAdd(&out[2 * i],     g0);
        atomicAdd(&out[2 * i + 1], g1);
        atomicAdd(&out[2 * j],     g0);
        atomicAdd(&out[2 * j + 1], g1);
    }
}

extern "C" void kernel_launch(void* const* d_in, const int* in_sizes, int n_in,
                              void* d_out, int out_size, void* d_ws, size_t ws_size,
                              hipStream_t stream) {
    const float* state   = (const float*)d_in[0];
    const float* actions = (const float*)d_in[1];
    const float* W1      = (const float*)d_in[2];
    const float* b1      = (const float*)d_in[3];
    const float* W2      = (const float*)d_in[4];
    const float* b2      = (const float*)d_in[5];
    const float* W3      = (const float*)d_in[6];
    const float* b3      = (const float*)d_in[7];
    float* out = (float*)d_out;
    float* h1  = (float*)d_ws;   // P*H floats = 4.16 MB

    l1_kernel <<<P_PAIRS, 256, 0, stream>>>(state, actions, W1, b1, h1, out);
    l23_kernel<<<P_PAIRS, 256, 0, stream>>>(h1, W2, b2, W3, b3, out);
}

// Round 4
// 199.937 us; speedup vs baseline: 1.1635x; 1.1381x over previous
//
#include <hip/hip_runtime.h>

#define N_AG    128
#define H_DIM   128
#define IN_DIM  132
#define P_PAIRS 8128   // 128*127/2
#define BLOCKS  1016   // P_PAIRS / 8 pairs-per-block

typedef float f32x4 __attribute__((ext_vector_type(4)));

// closed-form recovery of (i,j) from pair index p (np.triu_indices order)
__device__ __forceinline__ void pair_from_p(int p, int& i, int& j) {
    int t = P_PAIRS - 1 - p;                  // reverse index: t=0 is (N-2,N-1)
    float kf = (sqrtf(8.f * (float)t + 1.f) - 1.f) * 0.5f;
    int k = (int)kf;
    while ((k + 1) * (k + 2) / 2 <= t) ++k;   // fixup fp error
    while (k * (k + 1) / 2 > t) --k;
    i = N_AG - 2 - k;
    j = N_AG - 1 - (t - k * (k + 1) / 2);
}

__global__ void zero_out_kernel(float* out) { out[threadIdx.x] = 0.f; }

// One pair per 32-lane half-wave; thread owns output columns 4*lane..4*lane+3.
// 8 pairs per 256-thread block; whole grid (1016 blocks) resident at once.
__global__ __launch_bounds__(256) void fused_mlp_kernel(
    const float* __restrict__ state,
    const float* __restrict__ actions,
    const float* __restrict__ W1,
    const float* __restrict__ b1,
    const float* __restrict__ W2,
    const float* __restrict__ b2,
    const float* __restrict__ W3,
    const float* __restrict__ b3,
    float* __restrict__ out)
{
    const int t    = threadIdx.x;
    const int slot = t >> 5;            // pair slot within block, 0..7
    const int lane = t & 31;            // lane within half-wave
    const int p    = blockIdx.x * 8 + slot;

    __shared__ float xs[128];           // state, shared by all 8 pairs
    __shared__ float h1s[8][128];       // per-pair hidden 1

    if (t < 128) xs[t] = state[t];

    int i, j;
    pair_from_p(p, i, j);
    const float x128 = (float)i;
    const float x129 = (float)j;
    const float x130 = actions[i];
    const float x131 = actions[j];

    __syncthreads();

    // ---- layer 1: h1 = relu(x @ W1[p] + b1[p]) ----
    const f32x4* W1p = (const f32x4*)(W1 + (size_t)p * (IN_DIM * H_DIM));
    f32x4 acc = (f32x4)(0.f);
    #pragma unroll 16
    for (int r = 0; r < 128; ++r) {
        const float xv = xs[r];
        const f32x4 w = __builtin_nontemporal_load(&W1p[r * 32 + lane]);
        acc.x = fmaf(xv, w.x, acc.x);
        acc.y = fmaf(xv, w.y, acc.y);
        acc.z = fmaf(xv, w.z, acc.z);
        acc.w = fmaf(xv, w.w, acc.w);
    }
    {   // tail rows 128..131: [i, j, a_i, a_j]
        const f32x4 wA = __builtin_nontemporal_load(&W1p[128 * 32 + lane]);
        const f32x4 wB = __builtin_nontemporal_load(&W1p[129 * 32 + lane]);
        const f32x4 wC = __builtin_nontemporal_load(&W1p[130 * 32 + lane]);
        const f32x4 wD = __builtin_nontemporal_load(&W1p[131 * 32 + lane]);
        acc.x = fmaf(x128, wA.x, acc.x); acc.y = fmaf(x128, wA.y, acc.y);
        acc.z = fmaf(x128, wA.z, acc.z); acc.w = fmaf(x128, wA.w, acc.w);
        acc.x = fmaf(x129, wB.x, acc.x); acc.y = fmaf(x129, wB.y, acc.y);
        acc.z = fmaf(x129, wB.z, acc.z); acc.w = fmaf(x129, wB.w, acc.w);
        acc.x = fmaf(x130, wC.x, acc.x); acc.y = fmaf(x130, wC.y, acc.y);
        acc.z = fmaf(x130, wC.z, acc.z); acc.w = fmaf(x130, wC.w, acc.w);
        acc.x = fmaf(x131, wD.x, acc.x); acc.y = fmaf(x131, wD.y, acc.y);
        acc.z = fmaf(x131, wD.z, acc.z); acc.w = fmaf(x131, wD.w, acc.w);
    }
    const f32x4 b1v = *(const f32x4*)(b1 + (size_t)p * H_DIM + 4 * lane);
    f32x4 h1;
    h1.x = fmaxf(acc.x + b1v.x, 0.f);
    h1.y = fmaxf(acc.y + b1v.y, 0.f);
    h1.z = fmaxf(acc.z + b1v.z, 0.f);
    h1.w = fmaxf(acc.w + b1v.w, 0.f);
    *(f32x4*)&h1s[slot][4 * lane] = h1;
    __syncthreads();

    // ---- layer 2: h2 = relu(h1 @ W2[p] + b2[p]) ----
    const f32x4* W2p = (const f32x4*)(W2 + (size_t)p * (H_DIM * H_DIM));
    acc = (f32x4)(0.f);
    #pragma unroll 16
    for (int k = 0; k < 128; ++k) {
        const float hv = h1s[slot][k];
        const f32x4 w = __builtin_nontemporal_load(&W2p[k * 32 + lane]);
        acc.x = fmaf(hv, w.x, acc.x);
        acc.y = fmaf(hv, w.y, acc.y);
        acc.z = fmaf(hv, w.z, acc.z);
        acc.w = fmaf(hv, w.w, acc.w);
    }
    const f32x4 b2v = *(const f32x4*)(b2 + (size_t)p * H_DIM + 4 * lane);
    f32x4 h2;
    h2.x = fmaxf(acc.x + b2v.x, 0.f);
    h2.y = fmaxf(acc.y + b2v.y, 0.f);
    h2.z = fmaxf(acc.z + b2v.z, 0.f);
    h2.w = fmaxf(acc.w + b2v.w, 0.f);

    // ---- layer 3: logits over the thread's own 4 rows, then 32-lane reduce ----
    const f32x4* W3p = (const f32x4*)(W3 + (size_t)p * (H_DIM * 2));
    const f32x4 wa = __builtin_nontemporal_load(&W3p[2 * lane]);      // rows 4l,4l+1
    const f32x4 wb = __builtin_nontemporal_load(&W3p[2 * lane + 1]);  // rows 4l+2,4l+3
    float l0 = h2.x * wa.x + h2.y * wa.z + h2.z * wb.x + h2.w * wb.z;
    float l1 = h2.x * wa.y + h2.y * wa.w + h2.z * wb.y + h2.w * wb.w;
    #pragma unroll
    for (int off = 16; off > 0; off >>= 1) {
        l0 += __shfl_xor(l0, off, 32);
        l1 += __shfl_xor(l1, off, 32);
    }
    if (lane == 0) {
        l0 += b3[2 * p];
        l1 += b3[2 * p + 1];
        const float m  = fmaxf(l0, l1);
        const float e0 = expf(l0 - m), e1 = expf(l1 - m);
        const float inv = 1.f / (e0 + e1);
        const float g0 = e0 * inv, g1 = e1 * inv;
        atomicAdd(&out[2 * i],     g0);
        atomicAdd(&out[2 * i + 1], g1);
        atomicAdd(&out[2 * j],     g0);
        atomicAdd(&out[2 * j + 1], g1);
    }
}

extern "C" void kernel_launch(void* const* d_in, const int* in_sizes, int n_in,
                              void* d_out, int out_size, void* d_ws, size_t ws_size,
                              hipStream_t stream) {
    const float* state   = (const float*)d_in[0];
    const float* actions = (const float*)d_in[1];
    const float* W1      = (const float*)d_in[2];
    const float* b1      = (const float*)d_in[3];
    const float* W2      = (const float*)d_in[4];
    const float* b2      = (const float*)d_in[5];
    const float* W3      = (const float*)d_in[6];
    const float* b3      = (const float*)d_in[7];
    float* out = (float*)d_out;

    zero_out_kernel<<<1, 256, 0, stream>>>(out);
    fused_mlp_kernel<<<BLOCKS, 256, 0, stream>>>(
        state, actions, W1, b1, W2, b2, W3, b3, out);
}